// Round 4
// baseline (1528.185 us; speedup 1.0000x reference)
//
#include <hip/hip_runtime.h>

#define DDIM 128
#define HDIM 256
#define BQ   4
#define NN   4096
#define RTOT (BQ*NN)

typedef short short8 __attribute__((ext_vector_type(8)));
typedef float f32x16 __attribute__((ext_vector_type(16)));

// 3 staging buffers x 32KB (buf: [plane][seg0..3][col0..255] x 16B)
#define SIM_LDS_BYTES (3*32768)

__device__ inline unsigned short f2bf(float f) {
    unsigned int u = __float_as_uint(f);
    unsigned int r = (u + 0x7fffu + ((u >> 16) & 1u)) >> 16;
    return (unsigned short)r;
}
__device__ inline float bf2f(unsigned short h) {
    return __uint_as_float(((unsigned int)h) << 16);
}

// ---------------- fused sim (K K^T, split-bf16 MFMA, swapped operands) + per-row top-8 ----
// grid 256 (1 block/CU), block 256 (4 waves, PINNED 1 wave/EU -> 512-reg budget).
// Row keys (64 rows, full K=256, hi+lo) in registers as MFMA-B-operand; col keys streamed
// through wave-private LDS slices (global_load_lds w16, triple buffer, counted vmcnt,
// NO in-loop barriers). Output tile = sim^T -> per-row top-8 is lane-local in registers.
__global__ __launch_bounds__(256)
__attribute__((amdgpu_waves_per_eu(1, 1)))
void sim_topk_kernel(const unsigned short* __restrict__ khi,
                     const unsigned short* __restrict__ klo,
                     int* __restrict__ idxout) {
    extern __shared__ char smem[];

    const int id = blockIdx.x;
    const int b = (id & 7) >> 1;                    // XCD-pair -> batch (L2 locality)
    const int tile = ((id >> 3) << 1) | (id & 1);
    const int rowbase = tile * 64;
    const unsigned short* khiB = khi + (size_t)b * NN * HDIM;
    const unsigned short* kloB = klo + (size_t)b * NN * HDIM;

    const int tid = threadIdx.x;
    const int lane = tid & 63, w = tid >> 6;
    const int l31 = lane & 31, lh = lane >> 5;

    // ---- row keys (64 rows = 2 frags x 32, full K, hi+lo) in registers (B-operand) ----
    // lane holds rows (32m + l31), k-elems T*16 + lh*8 .. +8
    short8 ah[2][16], al[2][16];
    {
        const unsigned short* ph = khiB + (size_t)(rowbase + l31) * HDIM + lh * 8;
        const unsigned short* pl = kloB + (size_t)(rowbase + l31) * HDIM + lh * 8;
#pragma unroll
        for (int m = 0; m < 2; ++m)
#pragma unroll
            for (int T = 0; T < 16; ++T) {
                ah[m][T] = *(const short8*)(ph + (size_t)m * 32 * HDIM + T * 16);
                al[m][T] = *(const short8*)(pl + (size_t)m * 32 * HDIM + T * 16);
            }
    }
    // opaque def: blocks rematerialization of A-fragments from global inside the loop
#pragma unroll
    for (int m = 0; m < 2; ++m)
#pragma unroll
        for (int T = 0; T < 16; ++T) {
            asm volatile("" : "+v"(ah[m][T]));
            asm volatile("" : "+v"(al[m][T]));
        }

    // staging: wave w stages its own 64-col slice of step s=(cb,kb) into buf s%3.
    // LDS layout per buf: plane p (16KB) | seg 0..3 (4KB) | col (16B). Linear dest,
    // per-lane global source. seg = 2t+lh -> k-offset kb*32 + seg*8.
    auto stage = [&](int s) {
        const int cb2 = s >> 3, kb2 = s & 7;
        char* ldsb = smem + (s % 3) * 32768 + w * 1024;
        const size_t gcol = (size_t)(cb2 * 256 + w * 64 + lane);
        const unsigned short* srch = khiB + gcol * HDIM + kb2 * 32;
        const unsigned short* srcl = kloB + gcol * HDIM + kb2 * 32;
#pragma unroll
        for (int seg = 0; seg < 4; ++seg) {
            __builtin_amdgcn_global_load_lds(
                (const __attribute__((address_space(1))) void*)(srch + seg * 8),
                (__attribute__((address_space(3))) void*)(ldsb + seg * 4096), 16, 0, 0);
            __builtin_amdgcn_global_load_lds(
                (const __attribute__((address_space(1))) void*)(srcl + seg * 8),
                (__attribute__((address_space(3))) void*)(ldsb + 16384 + seg * 4096), 16, 0, 0);
        }
    };

    stage(0);
    stage(1);

    // per-lane running top-8 for rows 32m + l31 (m=0,1)
    float tv0[8], tv1[8]; int ti0[8], ti1[8];
#pragma unroll
    for (int s = 0; s < 8; ++s) {
        tv0[s] = -1e30f; ti0[s] = 0x7fffffff;
        tv1[s] = -1e30f; ti1[s] = 0x7fffffff;
    }

    f32x16 acc00, acc01, acc10, acc11;
#pragma unroll
    for (int r = 0; r < 16; ++r) { acc00[r]=0.f; acc01[r]=0.f; acc10[r]=0.f; acc11[r]=0.f; }

    const int rdoff = (w * 64 + l31) * 16 + lh * 4096;   // col-slice read base (n adds 512B)

    for (int cb = 0; cb < 16; ++cb) {
#pragma unroll
        for (int kb = 0; kb < 8; ++kb) {
            const int s = cb * 8 + kb;
            if (s + 2 < 128) stage(s + 2);
            if (s < 126)      asm volatile("s_waitcnt vmcnt(16)" ::: "memory");
            else if (s == 126) asm volatile("s_waitcnt vmcnt(8)" ::: "memory");
            else               asm volatile("s_waitcnt vmcnt(0)" ::: "memory");

            const char* bb = smem + (s % 3) * 32768 + rdoff;
#pragma unroll
            for (int t = 0; t < 2; ++t) {
                const int T = kb * 2 + t;
                const char* bt = bb + t * 8192;          // seg = 2t+lh -> (2t)*4096 + lh*4096
                // n = 0
                {
                    short8 bh = *(const short8*)(bt);
                    short8 bl = *(const short8*)(bt + 16384);
                    acc00 = __builtin_amdgcn_mfma_f32_32x32x16_bf16(bh, ah[0][T], acc00, 0, 0, 0);
                    acc00 = __builtin_amdgcn_mfma_f32_32x32x16_bf16(bh, al[0][T], acc00, 0, 0, 0);
                    acc00 = __builtin_amdgcn_mfma_f32_32x32x16_bf16(bl, ah[0][T], acc00, 0, 0, 0);
                    acc10 = __builtin_amdgcn_mfma_f32_32x32x16_bf16(bh, ah[1][T], acc10, 0, 0, 0);
                    acc10 = __builtin_amdgcn_mfma_f32_32x32x16_bf16(bh, al[1][T], acc10, 0, 0, 0);
                    acc10 = __builtin_amdgcn_mfma_f32_32x32x16_bf16(bl, ah[1][T], acc10, 0, 0, 0);
                }
                // n = 1
                {
                    short8 bh = *(const short8*)(bt + 512);
                    short8 bl = *(const short8*)(bt + 16384 + 512);
                    acc01 = __builtin_amdgcn_mfma_f32_32x32x16_bf16(bh, ah[0][T], acc01, 0, 0, 0);
                    acc01 = __builtin_amdgcn_mfma_f32_32x32x16_bf16(bh, al[0][T], acc01, 0, 0, 0);
                    acc01 = __builtin_amdgcn_mfma_f32_32x32x16_bf16(bl, ah[0][T], acc01, 0, 0, 0);
                    acc11 = __builtin_amdgcn_mfma_f32_32x32x16_bf16(bh, ah[1][T], acc11, 0, 0, 0);
                    acc11 = __builtin_amdgcn_mfma_f32_32x32x16_bf16(bh, al[1][T], acc11, 0, 0, 0);
                    acc11 = __builtin_amdgcn_mfma_f32_32x32x16_bf16(bl, ah[1][T], acc11, 0, 0, 0);
                }
            }
        }

        // scan this col-block's 64 lane-local sim values into per-row top-8 (ascending col
        // order per lane; strict > keeps lowest index on ties; cross-lane merge is lexicographic)
        const int cbase = cb * 256 + w * 64 + 4 * lh;
#pragma unroll
        for (int n = 0; n < 2; ++n) {
#pragma unroll
            for (int r = 0; r < 16; ++r) {
                const int col = cbase + n * 32 + (r & 3) + 8 * (r >> 2);
                // m = 0
                {
                    float v = (n == 0) ? acc00[r] : acc01[r];
                    if (v > tv0[7]) {
                        tv0[7] = v; ti0[7] = col;
#pragma unroll
                        for (int q = 7; q >= 1; --q) {
                            if (tv0[q] > tv0[q-1]) {
                                float a0 = tv0[q]; tv0[q] = tv0[q-1]; tv0[q-1] = a0;
                                int   c0 = ti0[q]; ti0[q] = ti0[q-1]; ti0[q-1] = c0;
                            }
                        }
                    }
                }
                // m = 1
                {
                    float v = (n == 0) ? acc10[r] : acc11[r];
                    if (v > tv1[7]) {
                        tv1[7] = v; ti1[7] = col;
#pragma unroll
                        for (int q = 7; q >= 1; --q) {
                            if (tv1[q] > tv1[q-1]) {
                                float a0 = tv1[q]; tv1[q] = tv1[q-1]; tv1[q-1] = a0;
                                int   c0 = ti1[q]; ti1[q] = ti1[q-1]; ti1[q-1] = c0;
                            }
                        }
                    }
                }
            }
        }
#pragma unroll
        for (int r = 0; r < 16; ++r) { acc00[r]=0.f; acc01[r]=0.f; acc10[r]=0.f; acc11[r]=0.f; }
    }

    // ---- merge 8 partial lists per row (4 waves x 2 half-waves), lexicographic ----
    __syncthreads();
    float* vbuf = (float*)smem;               // [64][66]
    int*   ibuf = (int*)(smem + 64*66*4);     // [64][66]
    const int list = w * 2 + lh;
#pragma unroll
    for (int s = 0; s < 8; ++s) {
        vbuf[(0*32 + l31)*66 + list*8 + s] = tv0[s];
        ibuf[(0*32 + l31)*66 + list*8 + s] = ti0[s];
        vbuf[(1*32 + l31)*66 + list*8 + s] = tv1[s];
        ibuf[(1*32 + l31)*66 + list*8 + s] = ti1[s];
    }
    __syncthreads();
    if (tid < 64) {
        float fv[8]; int fi[8];
#pragma unroll
        for (int s = 0; s < 8; ++s) { fv[s] = -1e30f; fi[s] = 0x7fffffff; }
        for (int e = 0; e < 64; ++e) {
            float v = vbuf[tid*66 + e];
            int  ix = ibuf[tid*66 + e];
            bool ins = (v > fv[7]) || (v == fv[7] && ix < fi[7]);
            if (ins) {
                fv[7] = v; fi[7] = ix;
#pragma unroll
                for (int q = 7; q >= 1; --q) {
                    bool sw = (fv[q] > fv[q-1]) || (fv[q] == fv[q-1] && fi[q] < fi[q-1]);
                    if (sw) {
                        float a0 = fv[q]; fv[q] = fv[q-1]; fv[q-1] = a0;
                        int   c0 = fi[q]; fi[q] = fi[q-1]; fi[q-1] = c0;
                    }
                }
            }
        }
        size_t basei = ((size_t)b*NN + rowbase + tid) * 8;
#pragma unroll
        for (int s = 0; s < 8; ++s) idxout[basei + s] = fi[s];
    }
}

// ---------------- keys projection GEMM + fused normalize -> khi/klo (bf16 planes) ----------------
__global__ __launch_bounds__(256, 2)
void gemm_keys(const float* __restrict__ A, const float* __restrict__ W,
               const float* __restrict__ bias,
               unsigned short* __restrict__ khi, unsigned short* __restrict__ klo) {
    __shared__ float As[32 * 132];
    int tid = threadIdx.x;
    size_t rowbase = (size_t)blockIdx.x * 32;
    for (int i = tid; i < 32 * 32; i += 256) {
        int r = i >> 5, q = i & 31;
        *(float4*)&As[r * 132 + q * 4] = *(const float4*)&A[(rowbase + r) * DDIM + q * 4];
    }
    __syncthreads();
    int rg = tid >> 5, cg = tid & 31;
    int r0 = rg * 4, c0 = cg * 8;
    float acc[4][8];
#pragma unroll
    for (int i = 0; i < 4; ++i)
#pragma unroll
        for (int j = 0; j < 8; ++j) acc[i][j] = 0.f;

#pragma unroll 2
    for (int k = 0; k < DDIM; k += 4) {
        float a[4][4];
#pragma unroll
        for (int i = 0; i < 4; ++i) {
            float4 t = *(const float4*)&As[(r0 + i) * 132 + k];
            a[i][0] = t.x; a[i][1] = t.y; a[i][2] = t.z; a[i][3] = t.w;
        }
#pragma unroll
        for (int kk = 0; kk < 4; ++kk) {
            float4 w0 = *(const float4*)&W[(size_t)(k + kk) * HDIM + c0];
            float4 w1 = *(const float4*)&W[(size_t)(k + kk) * HDIM + c0 + 4];
            float wv[8] = {w0.x, w0.y, w0.z, w0.w, w1.x, w1.y, w1.z, w1.w};
#pragma unroll
            for (int i = 0; i < 4; ++i)
#pragma unroll
                for (int j = 0; j < 8; ++j) acc[i][j] += a[i][kk] * wv[j];
        }
    }
    float4 bz0 = *(const float4*)&bias[c0];
    float4 bz1 = *(const float4*)&bias[c0 + 4];
    float bz[8] = {bz0.x, bz0.y, bz0.z, bz0.w, bz1.x, bz1.y, bz1.z, bz1.w};
#pragma unroll
    for (int i = 0; i < 4; ++i) {
        float vv[8];
        float ss = 0.f;
#pragma unroll
        for (int j = 0; j < 8; ++j) { vv[j] = acc[i][j] + bz[j]; ss += vv[j]*vv[j]; }
#pragma unroll
        for (int m = 16; m; m >>= 1) ss += __shfl_xor(ss, m);
        float sc = 1.0f / fmaxf(sqrtf(ss), 1e-12f);
        short8 hv, lv;
#pragma unroll
        for (int j = 0; j < 8; ++j) {
            float vn = vv[j] * sc;
            unsigned short h = f2bf(vn);
            hv[j] = (short)h;
            lv[j] = (short)f2bf(vn - bf2f(h));
        }
        *(short8*)&khi[(rowbase + r0 + i) * HDIM + c0] = hv;
        *(short8*)&klo[(rowbase + r0 + i) * HDIM + c0] = lv;
    }
}

// ---------------- agg projection GEMM: out = A(Rx128) @ W(128x256) + bias ----------------
__global__ __launch_bounds__(256, 2)
void gemm_d_h(const float* __restrict__ A, const float* __restrict__ W,
              const float* __restrict__ bias, float* __restrict__ out) {
    __shared__ float As[32 * 132];
    int tid = threadIdx.x;
    size_t rowbase = (size_t)blockIdx.x * 32;
    for (int i = tid; i < 32 * 32; i += 256) {
        int r = i >> 5, q = i & 31;
        *(float4*)&As[r * 132 + q * 4] = *(const float4*)&A[(rowbase + r) * DDIM + q * 4];
    }
    __syncthreads();
    int rg = tid >> 5, cg = tid & 31;
    int r0 = rg * 4, c0 = cg * 8;
    float acc[4][8];
#pragma unroll
    for (int i = 0; i < 4; ++i)
#pragma unroll
        for (int j = 0; j < 8; ++j) acc[i][j] = 0.f;

#pragma unroll 2
    for (int k = 0; k < DDIM; k += 4) {
        float a[4][4];
#pragma unroll
        for (int i = 0; i < 4; ++i) {
            float4 t = *(const float4*)&As[(r0 + i) * 132 + k];
            a[i][0] = t.x; a[i][1] = t.y; a[i][2] = t.z; a[i][3] = t.w;
        }
#pragma unroll
        for (int kk = 0; kk < 4; ++kk) {
            float4 w0 = *(const float4*)&W[(size_t)(k + kk) * HDIM + c0];
            float4 w1 = *(const float4*)&W[(size_t)(k + kk) * HDIM + c0 + 4];
            float wv[8] = {w0.x, w0.y, w0.z, w0.w, w1.x, w1.y, w1.z, w1.w};
#pragma unroll
            for (int i = 0; i < 4; ++i)
#pragma unroll
                for (int j = 0; j < 8; ++j) acc[i][j] += a[i][kk] * wv[j];
        }
    }
    float4 bz0 = *(const float4*)&bias[c0];
    float4 bz1 = *(const float4*)&bias[c0 + 4];
    float bz[8] = {bz0.x, bz0.y, bz0.z, bz0.w, bz1.x, bz1.y, bz1.z, bz1.w};
#pragma unroll
    for (int i = 0; i < 4; ++i) {
        float4 o0, o1;
        o0.x = acc[i][0] + bz[0]; o0.y = acc[i][1] + bz[1]; o0.z = acc[i][2] + bz[2]; o0.w = acc[i][3] + bz[3];
        o1.x = acc[i][4] + bz[4]; o1.y = acc[i][5] + bz[5]; o1.z = acc[i][6] + bz[6]; o1.w = acc[i][7] + bz[7];
        *(float4*)&out[(rowbase + r0 + i) * HDIM + c0] = o0;
        *(float4*)&out[(rowbase + r0 + i) * HDIM + c0 + 4] = o1;
    }
}

// ---------------- gather top-8 rows + mean, 2 rows / block ----------------
__global__ void gather_mean_kernel(const float* __restrict__ state, const int* __restrict__ idx,
                                   float* __restrict__ M) {
    __shared__ int ilds[16];
    int tid = threadIdx.x;
    int row0 = blockIdx.x * 2;
    if (tid < 16) ilds[tid] = idx[(size_t)row0 * 8 + tid];
    __syncthreads();
    int lr = tid >> 7, d = tid & 127;
    int grow = row0 + lr;
    int b = grow >> 12;
    const float* sb = state + (size_t)b * NN * DDIM;
    float acc = 0.f;
#pragma unroll
    for (int k = 0; k < 8; ++k) acc += sb[(size_t)ilds[lr * 8 + k] * DDIM + d];
    M[(size_t)grow * DDIM + d] = acc * 0.125f;
}

// ---------------- concat GEMM (K=384) + LayerNorm epilogue ----------------
__global__ __launch_bounds__(256, 2)
void gemm_ln(const float* __restrict__ state, const float* __restrict__ agg,
             const float* __restrict__ W1, const float* __restrict__ b1,
             const float* __restrict__ lng, const float* __restrict__ lnb,
             float* __restrict__ h) {
    __shared__ float As[32 * 388];
    int tid = threadIdx.x;
    size_t rowbase = (size_t)blockIdx.x * 32;
    for (int i = tid; i < 32 * 96; i += 256) {
        int r = i / 96, q = i % 96;
        float4 v;
        if (q < 32) v = *(const float4*)&state[(rowbase + r) * DDIM + q * 4];
        else        v = *(const float4*)&agg[(rowbase + r) * HDIM + (q - 32) * 4];
        *(float4*)&As[r * 388 + q * 4] = v;
    }
    __syncthreads();
    int rg = tid >> 5, cg = tid & 31;
    int r0 = rg * 4, c0 = cg * 8;
    float acc[4][8];
#pragma unroll
    for (int i = 0; i < 4; ++i)
#pragma unroll
        for (int j = 0; j < 8; ++j) acc[i][j] = 0.f;

#pragma unroll 2
    for (int k = 0; k < 384; k += 4) {
        float a[4][4];
#pragma unroll
        for (int i = 0; i < 4; ++i) {
            float4 t = *(const float4*)&As[(r0 + i) * 388 + k];
            a[i][0] = t.x; a[i][1] = t.y; a[i][2] = t.z; a[i][3] = t.w;
        }
#pragma unroll
        for (int kk = 0; kk < 4; ++kk) {
            float4 w0 = *(const float4*)&W1[(size_t)(k + kk) * HDIM + c0];
            float4 w1 = *(const float4*)&W1[(size_t)(k + kk) * HDIM + c0 + 4];
            float wv[8] = {w0.x, w0.y, w0.z, w0.w, w1.x, w1.y, w1.z, w1.w};
#pragma unroll
            for (int i = 0; i < 4; ++i)
#pragma unroll
                for (int j = 0; j < 8; ++j) acc[i][j] += a[i][kk] * wv[j];
        }
    }
    float4 b10 = *(const float4*)&b1[c0];
    float4 b11 = *(const float4*)&b1[c0 + 4];
    float bb[8] = {b10.x, b10.y, b10.z, b10.w, b11.x, b11.y, b11.z, b11.w};
    float4 g0 = *(const float4*)&lng[c0];
    float4 g1 = *(const float4*)&lng[c0 + 4];
    float lg[8] = {g0.x, g0.y, g0.z, g0.w, g1.x, g1.y, g1.z, g1.w};
    float4 e0 = *(const float4*)&lnb[c0];
    float4 e1 = *(const float4*)&lnb[c0 + 4];
    float lb[8] = {e0.x, e0.y, e0.z, e0.w, e1.x, e1.y, e1.z, e1.w};

#pragma unroll
    for (int i = 0; i < 4; ++i) {
        float s1 = 0.f, s2 = 0.f;
#pragma unroll
        for (int j = 0; j < 8; ++j) {
            acc[i][j] += bb[j];
            s1 += acc[i][j];
            s2 += acc[i][j] * acc[i][j];
        }
#pragma unroll
        for (int m = 16; m; m >>= 1) { s1 += __shfl_xor(s1, m); s2 += __shfl_xor(s2, m); }
        float mu = s1 * (1.0f / HDIM);
        float var = s2 * (1.0f / HDIM) - mu * mu;
        float inv = 1.0f / sqrtf(var + 1e-5f);
        float4 o0, o1;
        o0.x = (acc[i][0] - mu) * inv * lg[0] + lb[0];
        o0.y = (acc[i][1] - mu) * inv * lg[1] + lb[1];
        o0.z = (acc[i][2] - mu) * inv * lg[2] + lb[2];
        o0.w = (acc[i][3] - mu) * inv * lg[3] + lb[3];
        o1.x = (acc[i][4] - mu) * inv * lg[4] + lb[4];
        o1.y = (acc[i][5] - mu) * inv * lg[5] + lb[5];
        o1.z = (acc[i][6] - mu) * inv * lg[6] + lb[6];
        o1.w = (acc[i][7] - mu) * inv * lg[7] + lb[7];
        *(float4*)&h[(rowbase + r0 + i) * HDIM + c0] = o0;
        *(float4*)&h[(rowbase + r0 + i) * HDIM + c0 + 4] = o1;
    }
}

// ---------------- update GEMM: state += silu(h) @ W2 + b2 ----------------
__global__ __launch_bounds__(256, 2)
void gemm_upd(const float* __restrict__ h, const float* __restrict__ W2,
              const float* __restrict__ b2, float* __restrict__ state) {
    __shared__ float As[32 * 260];
    int tid = threadIdx.x;
    size_t rowbase = (size_t)blockIdx.x * 32;
    for (int i = tid; i < 32 * 64; i += 256) {
        int r = i >> 6, q = i & 63;
        float4 v = *(const float4*)&h[(rowbase + r) * HDIM + q * 4];
        v.x = v.x / (1.0f + expf(-v.x));
        v.y = v.y / (1.0f + expf(-v.y));
        v.z = v.z / (1.0f + expf(-v.z));
        v.w = v.w / (1.0f + expf(-v.w));
        *(float4*)&As[r * 260 + q * 4] = v;
    }
    __syncthreads();
    int rg = tid >> 4, cg = tid & 15;
    int r0 = rg * 2, c0 = cg * 8;
    float acc[2][8];
#pragma unroll
    for (int i = 0; i < 2; ++i)
#pragma unroll
        for (int j = 0; j < 8; ++j) acc[i][j] = 0.f;

#pragma unroll 2
    for (int k = 0; k < HDIM; k += 4) {
        float a[2][4];
#pragma unroll
        for (int i = 0; i < 2; ++i) {
            float4 t = *(const float4*)&As[(r0 + i) * 260 + k];
            a[i][0] = t.x; a[i][1] = t.y; a[i][2] = t.z; a[i][3] = t.w;
        }
#pragma unroll
        for (int kk = 0; kk < 4; ++kk) {
            float4 w0 = *(const float4*)&W2[(size_t)(k + kk) * DDIM + c0];
            float4 w1 = *(const float4*)&W2[(size_t)(k + kk) * DDIM + c0 + 4];
            float wv[8] = {w0.x, w0.y, w0.z, w0.w, w1.x, w1.y, w1.z, w1.w};
#pragma unroll
            for (int i = 0; i < 2; ++i)
#pragma unroll
                for (int j = 0; j < 8; ++j) acc[i][j] += a[i][kk] * wv[j];
        }
    }
    float4 bz0 = *(const float4*)&b2[c0];
    float4 bz1 = *(const float4*)&b2[c0 + 4];
    float bz[8] = {bz0.x, bz0.y, bz0.z, bz0.w, bz1.x, bz1.y, bz1.z, bz1.w};
#pragma unroll
    for (int i = 0; i < 2; ++i) {
        size_t off = (rowbase + r0 + i) * DDIM + c0;
        float4 s0 = *(const float4*)&state[off];
        float4 s1 = *(const float4*)&state[off + 4];
        s0.x += acc[i][0] + bz[0]; s0.y += acc[i][1] + bz[1];
        s0.z += acc[i][2] + bz[2]; s0.w += acc[i][3] + bz[3];
        s1.x += acc[i][4] + bz[4]; s1.y += acc[i][5] + bz[5];
        s1.z += acc[i][6] + bz[6]; s1.w += acc[i][7] + bz[7];
        *(float4*)&state[off] = s0;
        *(float4*)&state[off + 4] = s1;
    }
}

// ---------------- final: mean over N, then @ Wo + bo ----------------
__global__ void partial_mean_kernel(const float* __restrict__ state, float* __restrict__ partial) {
    int b = blockIdx.y, seg = blockIdx.x, tid = threadIdx.x;  // 128 threads
    const float* sp = state + ((size_t)b * NN + (size_t)seg * 128) * DDIM;
    float acc = 0.f;
    for (int i = 0; i < 128; ++i) acc += sp[(size_t)i * DDIM + tid];
    partial[((size_t)b * 32 + seg) * DDIM + tid] = acc;
}

__global__ void final_out_kernel(const float* __restrict__ partial, const float* __restrict__ Wo,
                                 const float* __restrict__ bo, float* __restrict__ out) {
    __shared__ float mean[BQ][DDIM];
    int tid = threadIdx.x;
    for (int o = tid; o < BQ * DDIM; o += 256) {
        int b = o >> 7, d = o & 127;
        float s = 0.f;
        for (int p = 0; p < 32; ++p) s += partial[((size_t)b * 32 + p) * DDIM + d];
        mean[b][d] = s * (1.0f / NN);
    }
    __syncthreads();
    for (int o = tid; o < BQ * DDIM; o += 256) {
        int b = o >> 7, c = o & 127;
        float acc = bo[c];
        for (int d = 0; d < DDIM; ++d) acc += mean[b][d] * Wo[d * DDIM + c];
        out[o] = acc;
    }
}

extern "C" void kernel_launch(void* const* d_in, const int* in_sizes, int n_in,
                              void* d_out, int out_size, void* d_ws, size_t ws_size,
                              hipStream_t stream) {
    const float* x   = (const float*)d_in[0];
    const float* Wn  = (const float*)d_in[1];
    const float* bn  = (const float*)d_in[2];
    const float* W1  = (const float*)d_in[3];
    const float* b1  = (const float*)d_in[4];
    const float* lng = (const float*)d_in[5];
    const float* lnb = (const float*)d_in[6];
    const float* W2  = (const float*)d_in[7];
    const float* b2  = (const float*)d_in[8];
    const float* Wo  = (const float*)d_in[9];
    const float* bo  = (const float*)d_in[10];
    float* out = (float*)d_out;

    float* ws      = (float*)d_ws;
    float* state   = ws;                                        // R*128 f32
    float* keysagg = state + (size_t)RTOT * DDIM;               // R*256 f32
    float* hbuf    = keysagg + (size_t)RTOT * HDIM;             // R*256 f32
    unsigned short* khi_b = (unsigned short*)hbuf;              // R*256 bf16
    unsigned short* klo_b = khi_b + (size_t)RTOT * HDIM;        // R*256 bf16
    float* Mbuf    = hbuf;                                      // R*128 f32 (after sim)
    float* partial = hbuf + (size_t)RTOT * HDIM;                // B*32*128
    int*   idxbuf  = (int*)(partial + (size_t)BQ * 32 * DDIM);  // R*8 ints

    hipMemcpyAsync(state, x, (size_t)RTOT * DDIM * sizeof(float),
                   hipMemcpyDeviceToDevice, stream);

    (void)hipFuncSetAttribute((const void*)sim_topk_kernel,
                              hipFuncAttributeMaxDynamicSharedMemorySize,
                              SIM_LDS_BYTES);

    for (int step = 0; step < 3; ++step) {
        gemm_keys<<<RTOT / 32, 256, 0, stream>>>(state, Wn, bn, khi_b, klo_b);
        sim_topk_kernel<<<256, 256, SIM_LDS_BYTES, stream>>>(khi_b, klo_b, idxbuf);
        gather_mean_kernel<<<RTOT / 2, 256, 0, stream>>>(state, idxbuf, Mbuf);
        gemm_d_h<<<RTOT / 32, 256, 0, stream>>>(Mbuf, Wn, bn, keysagg);
        gemm_ln<<<RTOT / 32, 256, 0, stream>>>(state, keysagg, W1, b1, lng, lnb, hbuf);
        gemm_upd<<<RTOT / 32, 256, 0, stream>>>(hbuf, W2, b2, state);
    }
    partial_mean_kernel<<<dim3(32, BQ), 128, 0, stream>>>(state, partial);
    final_out_kernel<<<1, 256, 0, stream>>>(partial, Wo, bo, out);
}

// Round 5
// 1393.690 us; speedup vs baseline: 1.0965x; 1.0965x over previous
//
#include <hip/hip_runtime.h>

#define DDIM 128
#define HDIM 256
#define BQ   4
#define NN   4096
#define RTOT (BQ*NN)

typedef short short8 __attribute__((ext_vector_type(8)));
typedef float f32x16 __attribute__((ext_vector_type(16)));

__device__ inline unsigned short f2bf(float f) {
    unsigned int u = __float_as_uint(f);
    unsigned int r = (u + 0x7fffu + ((u >> 16) & 1u)) >> 16;
    return (unsigned short)r;
}
__device__ inline float bf2f(unsigned short h) {
    return __uint_as_float(((unsigned int)h) << 16);
}

// ---------------- fused sim (K K^T, split-bf16 MFMA, swapped operands) + per-row top-8 ----
// grid 512 (2 blocks/CU), block 256 = 4 waves, 2 waves/SIMD (launch_bounds(256,2)).
// Block = 32 rows x 4096 cols; wave = 32 rows x 1024 cols (col-split), full K=256.
// Row keys (32 rows, hi+lo) in registers (128 VGPR); col keys streamed DIRECTLY from
// L2 to registers (no LDS staging -- reuse per staged byte was 1, LDS was pure overhead).
// No barriers until the final 8-list merge. Output tile = sim^T: top-8 is lane-local.
__global__ __launch_bounds__(256, 2)
void sim_topk_kernel(const unsigned short* __restrict__ khi,
                     const unsigned short* __restrict__ klo,
                     int* __restrict__ idxout) {
    __shared__ float vbuf[32 * 66];
    __shared__ int   ibuf[32 * 66];

    const int id = blockIdx.x;
    const int xcd = id & 7;
    const int b = xcd >> 1;                       // batch -> XCD pair (L2 residency, perf-only)
    const int j = ((id >> 3) << 1) | (xcd & 1);   // tile within batch, 0..127
    const int rowbase = j * 32;
    const unsigned short* khiB = khi + (size_t)b * NN * HDIM;
    const unsigned short* kloB = klo + (size_t)b * NN * HDIM;

    const int tid = threadIdx.x;
    const int lane = tid & 63, w = tid >> 6;
    const int l31 = lane & 31, lh = lane >> 5;

    // ---- row keys (32 rows, full K, hi+lo) in registers (MFMA B-operand) ----
    // lane: l31 -> row rowbase+l31; lh -> k-half; frag T covers k [T*16, T*16+16)
    short8 ah[16], al[16];
    {
        const unsigned short* ph = khiB + (size_t)(rowbase + l31) * HDIM + lh * 8;
        const unsigned short* pl = kloB + (size_t)(rowbase + l31) * HDIM + lh * 8;
#pragma unroll
        for (int T = 0; T < 16; ++T) {
            ah[T] = *(const short8*)(ph + T * 16);
            al[T] = *(const short8*)(pl + T * 16);
        }
    }
#pragma unroll
    for (int T = 0; T < 16; ++T) {
        asm volatile("" : "+v"(ah[T]));
        asm volatile("" : "+v"(al[T]));
    }

    // ---- col-key stream base pointers (this wave's 64-col slice per cb) ----
    // col = cb*256 + w*64 + f*32 + l31 ; k = kb*32 + t*16 + lh*8
    const unsigned short* pH = khiB + (size_t)(w * 64 + l31) * HDIM + lh * 8;
    const unsigned short* pL = kloB + (size_t)(w * 64 + l31) * HDIM + lh * 8;

    // per-lane running top-8 (row l31; lanes lh=0/1 hold disjoint col subsets)
    float tv[8]; int ti[8];
#pragma unroll
    for (int s = 0; s < 8; ++s) { tv[s] = -1e30f; ti[s] = 0x7fffffff; }

    for (int cb = 0; cb < 16; ++cb) {
        const unsigned short* qH = pH + (size_t)cb * 256 * HDIM;
        const unsigned short* qL = pL + (size_t)cb * 256 * HDIM;

        f32x16 acc0, acc1;
#pragma unroll
        for (int r = 0; r < 16; ++r) { acc0[r] = 0.f; acc1[r] = 0.f; }

#pragma unroll
        for (int f = 0; f < 2; ++f) {
            const unsigned short* qHf = qH + f * 32 * HDIM;
            const unsigned short* qLf = qL + f * 32 * HDIM;
#pragma unroll
            for (int kb = 0; kb < 8; ++kb) {
#pragma unroll
                for (int t = 0; t < 2; ++t) {
                    const int T = kb * 2 + t;
                    short8 bh = *(const short8*)(qHf + kb * 32 + t * 16);
                    short8 bl = *(const short8*)(qLf + kb * 32 + t * 16);
                    if (f == 0) {
                        acc0 = __builtin_amdgcn_mfma_f32_32x32x16_bf16(bh, ah[T], acc0, 0, 0, 0);
                        acc0 = __builtin_amdgcn_mfma_f32_32x32x16_bf16(bh, al[T], acc0, 0, 0, 0);
                        acc0 = __builtin_amdgcn_mfma_f32_32x32x16_bf16(bl, ah[T], acc0, 0, 0, 0);
                    } else {
                        acc1 = __builtin_amdgcn_mfma_f32_32x32x16_bf16(bh, ah[T], acc1, 0, 0, 0);
                        acc1 = __builtin_amdgcn_mfma_f32_32x32x16_bf16(bh, al[T], acc1, 0, 0, 0);
                        acc1 = __builtin_amdgcn_mfma_f32_32x32x16_bf16(bl, ah[T], acc1, 0, 0, 0);
                    }
                }
            }
        }

        // scan (ascending col order per lane; strict > keeps lowest index on ties)
        const int cbase = cb * 256 + w * 64 + 4 * lh;
#pragma unroll
        for (int f = 0; f < 2; ++f) {
#pragma unroll
            for (int r = 0; r < 16; ++r) {
                const int col = cbase + f * 32 + (r & 3) + 8 * (r >> 2);
                float v = (f == 0) ? acc0[r] : acc1[r];
                if (v > tv[7]) {
                    tv[7] = v; ti[7] = col;
#pragma unroll
                    for (int q = 7; q >= 1; --q) {
                        if (tv[q] > tv[q - 1]) {
                            float a0 = tv[q]; tv[q] = tv[q - 1]; tv[q - 1] = a0;
                            int   c0 = ti[q]; ti[q] = ti[q - 1]; ti[q - 1] = c0;
                        }
                    }
                }
            }
        }
    }

    // ---- merge 8 partial lists per row (4 waves x 2 lh), lexicographic ----
    const int list = w * 2 + lh;
#pragma unroll
    for (int s = 0; s < 8; ++s) {
        vbuf[l31 * 66 + list * 8 + s] = tv[s];
        ibuf[l31 * 66 + list * 8 + s] = ti[s];
    }
    __syncthreads();
    if (tid < 32) {
        float fv[8]; int fi[8];
#pragma unroll
        for (int s = 0; s < 8; ++s) { fv[s] = -1e30f; fi[s] = 0x7fffffff; }
        for (int e = 0; e < 64; ++e) {
            float v = vbuf[tid * 66 + e];
            int  ix = ibuf[tid * 66 + e];
            bool ins = (v > fv[7]) || (v == fv[7] && ix < fi[7]);
            if (ins) {
                fv[7] = v; fi[7] = ix;
#pragma unroll
                for (int q = 7; q >= 1; --q) {
                    bool sw = (fv[q] > fv[q - 1]) || (fv[q] == fv[q - 1] && fi[q] < fi[q - 1]);
                    if (sw) {
                        float a0 = fv[q]; fv[q] = fv[q - 1]; fv[q - 1] = a0;
                        int   c0 = fi[q]; fi[q] = fi[q - 1]; fi[q - 1] = c0;
                    }
                }
            }
        }
        size_t basei = ((size_t)b * NN + rowbase + tid) * 8;
#pragma unroll
        for (int s = 0; s < 8; ++s) idxout[basei + s] = fi[s];
    }
}

// ---------------- keys projection GEMM + fused normalize -> khi/klo (bf16 planes) ----------------
__global__ __launch_bounds__(256, 2)
void gemm_keys(const float* __restrict__ A, const float* __restrict__ W,
               const float* __restrict__ bias,
               unsigned short* __restrict__ khi, unsigned short* __restrict__ klo) {
    __shared__ float As[32 * 132];
    int tid = threadIdx.x;
    size_t rowbase = (size_t)blockIdx.x * 32;
    for (int i = tid; i < 32 * 32; i += 256) {
        int r = i >> 5, q = i & 31;
        *(float4*)&As[r * 132 + q * 4] = *(const float4*)&A[(rowbase + r) * DDIM + q * 4];
    }
    __syncthreads();
    int rg = tid >> 5, cg = tid & 31;
    int r0 = rg * 4, c0 = cg * 8;
    float acc[4][8];
#pragma unroll
    for (int i = 0; i < 4; ++i)
#pragma unroll
        for (int j = 0; j < 8; ++j) acc[i][j] = 0.f;

#pragma unroll 2
    for (int k = 0; k < DDIM; k += 4) {
        float a[4][4];
#pragma unroll
        for (int i = 0; i < 4; ++i) {
            float4 t = *(const float4*)&As[(r0 + i) * 132 + k];
            a[i][0] = t.x; a[i][1] = t.y; a[i][2] = t.z; a[i][3] = t.w;
        }
#pragma unroll
        for (int kk = 0; kk < 4; ++kk) {
            float4 w0 = *(const float4*)&W[(size_t)(k + kk) * HDIM + c0];
            float4 w1 = *(const float4*)&W[(size_t)(k + kk) * HDIM + c0 + 4];
            float wv[8] = {w0.x, w0.y, w0.z, w0.w, w1.x, w1.y, w1.z, w1.w};
#pragma unroll
            for (int i = 0; i < 4; ++i)
#pragma unroll
                for (int j = 0; j < 8; ++j) acc[i][j] += a[i][kk] * wv[j];
        }
    }
    float4 bz0 = *(const float4*)&bias[c0];
    float4 bz1 = *(const float4*)&bias[c0 + 4];
    float bz[8] = {bz0.x, bz0.y, bz0.z, bz0.w, bz1.x, bz1.y, bz1.z, bz1.w};
#pragma unroll
    for (int i = 0; i < 4; ++i) {
        float vv[8];
        float ss = 0.f;
#pragma unroll
        for (int j = 0; j < 8; ++j) { vv[j] = acc[i][j] + bz[j]; ss += vv[j]*vv[j]; }
#pragma unroll
        for (int m = 16; m; m >>= 1) ss += __shfl_xor(ss, m);
        float sc = 1.0f / fmaxf(sqrtf(ss), 1e-12f);
        short8 hv, lv;
#pragma unroll
        for (int j = 0; j < 8; ++j) {
            float vn = vv[j] * sc;
            unsigned short h = f2bf(vn);
            hv[j] = (short)h;
            lv[j] = (short)f2bf(vn - bf2f(h));
        }
        *(short8*)&khi[(rowbase + r0 + i) * HDIM + c0] = hv;
        *(short8*)&klo[(rowbase + r0 + i) * HDIM + c0] = lv;
    }
}

// ---------------- agg projection GEMM: out = A(Rx128) @ W(128x256) + bias ----------------
__global__ __launch_bounds__(256, 2)
void gemm_d_h(const float* __restrict__ A, const float* __restrict__ W,
              const float* __restrict__ bias, float* __restrict__ out) {
    __shared__ float As[32 * 132];
    int tid = threadIdx.x;
    size_t rowbase = (size_t)blockIdx.x * 32;
    for (int i = tid; i < 32 * 32; i += 256) {
        int r = i >> 5, q = i & 31;
        *(float4*)&As[r * 132 + q * 4] = *(const float4*)&A[(rowbase + r) * DDIM + q * 4];
    }
    __syncthreads();
    int rg = tid >> 5, cg = tid & 31;
    int r0 = rg * 4, c0 = cg * 8;
    float acc[4][8];
#pragma unroll
    for (int i = 0; i < 4; ++i)
#pragma unroll
        for (int j = 0; j < 8; ++j) acc[i][j] = 0.f;

#pragma unroll 2
    for (int k = 0; k < DDIM; k += 4) {
        float a[4][4];
#pragma unroll
        for (int i = 0; i < 4; ++i) {
            float4 t = *(const float4*)&As[(r0 + i) * 132 + k];
            a[i][0] = t.x; a[i][1] = t.y; a[i][2] = t.z; a[i][3] = t.w;
        }
#pragma unroll
        for (int kk = 0; kk < 4; ++kk) {
            float4 w0 = *(const float4*)&W[(size_t)(k + kk) * HDIM + c0];
            float4 w1 = *(const float4*)&W[(size_t)(k + kk) * HDIM + c0 + 4];
            float wv[8] = {w0.x, w0.y, w0.z, w0.w, w1.x, w1.y, w1.z, w1.w};
#pragma unroll
            for (int i = 0; i < 4; ++i)
#pragma unroll
                for (int j = 0; j < 8; ++j) acc[i][j] += a[i][kk] * wv[j];
        }
    }
    float4 bz0 = *(const float4*)&bias[c0];
    float4 bz1 = *(const float4*)&bias[c0 + 4];
    float bz[8] = {bz0.x, bz0.y, bz0.z, bz0.w, bz1.x, bz1.y, bz1.z, bz1.w};
#pragma unroll
    for (int i = 0; i < 4; ++i) {
        float4 o0, o1;
        o0.x = acc[i][0] + bz[0]; o0.y = acc[i][1] + bz[1]; o0.z = acc[i][2] + bz[2]; o0.w = acc[i][3] + bz[3];
        o1.x = acc[i][4] + bz[4]; o1.y = acc[i][5] + bz[5]; o1.z = acc[i][6] + bz[6]; o1.w = acc[i][7] + bz[7];
        *(float4*)&out[(rowbase + r0 + i) * HDIM + c0] = o0;
        *(float4*)&out[(rowbase + r0 + i) * HDIM + c0 + 4] = o1;
    }
}

// ---------------- gather top-8 rows + mean, 2 rows / block ----------------
__global__ void gather_mean_kernel(const float* __restrict__ state, const int* __restrict__ idx,
                                   float* __restrict__ M) {
    __shared__ int ilds[16];
    int tid = threadIdx.x;
    int row0 = blockIdx.x * 2;
    if (tid < 16) ilds[tid] = idx[(size_t)row0 * 8 + tid];
    __syncthreads();
    int lr = tid >> 7, d = tid & 127;
    int grow = row0 + lr;
    int b = grow >> 12;
    const float* sb = state + (size_t)b * NN * DDIM;
    float acc = 0.f;
#pragma unroll
    for (int k = 0; k < 8; ++k) acc += sb[(size_t)ilds[lr * 8 + k] * DDIM + d];
    M[(size_t)grow * DDIM + d] = acc * 0.125f;
}

// ---------------- concat GEMM (K=384) + LayerNorm epilogue ----------------
__global__ __launch_bounds__(256, 2)
void gemm_ln(const float* __restrict__ state, const float* __restrict__ agg,
             const float* __restrict__ W1, const float* __restrict__ b1,
             const float* __restrict__ lng, const float* __restrict__ lnb,
             float* __restrict__ h) {
    __shared__ float As[32 * 388];
    int tid = threadIdx.x;
    size_t rowbase = (size_t)blockIdx.x * 32;
    for (int i = tid; i < 32 * 96; i += 256) {
        int r = i / 96, q = i % 96;
        float4 v;
        if (q < 32) v = *(const float4*)&state[(rowbase + r) * DDIM + q * 4];
        else        v = *(const float4*)&agg[(rowbase + r) * HDIM + (q - 32) * 4];
        *(float4*)&As[r * 388 + q * 4] = v;
    }
    __syncthreads();
    int rg = tid >> 5, cg = tid & 31;
    int r0 = rg * 4, c0 = cg * 8;
    float acc[4][8];
#pragma unroll
    for (int i = 0; i < 4; ++i)
#pragma unroll
        for (int j = 0; j < 8; ++j) acc[i][j] = 0.f;

#pragma unroll 2
    for (int k = 0; k < 384; k += 4) {
        float a[4][4];
#pragma unroll
        for (int i = 0; i < 4; ++i) {
            float4 t = *(const float4*)&As[(r0 + i) * 388 + k];
            a[i][0] = t.x; a[i][1] = t.y; a[i][2] = t.z; a[i][3] = t.w;
        }
#pragma unroll
        for (int kk = 0; kk < 4; ++kk) {
            float4 w0 = *(const float4*)&W1[(size_t)(k + kk) * HDIM + c0];
            float4 w1 = *(const float4*)&W1[(size_t)(k + kk) * HDIM + c0 + 4];
            float wv[8] = {w0.x, w0.y, w0.z, w0.w, w1.x, w1.y, w1.z, w1.w};
#pragma unroll
            for (int i = 0; i < 4; ++i)
#pragma unroll
                for (int j = 0; j < 8; ++j) acc[i][j] += a[i][kk] * wv[j];
        }
    }
    float4 b10 = *(const float4*)&b1[c0];
    float4 b11 = *(const float4*)&b1[c0 + 4];
    float bb[8] = {b10.x, b10.y, b10.z, b10.w, b11.x, b11.y, b11.z, b11.w};
    float4 g0 = *(const float4*)&lng[c0];
    float4 g1 = *(const float4*)&lng[c0 + 4];
    float lg[8] = {g0.x, g0.y, g0.z, g0.w, g1.x, g1.y, g1.z, g1.w};
    float4 e0 = *(const float4*)&lnb[c0];
    float4 e1 = *(const float4*)&lnb[c0 + 4];
    float lb[8] = {e0.x, e0.y, e0.z, e0.w, e1.x, e1.y, e1.z, e1.w};

#pragma unroll
    for (int i = 0; i < 4; ++i) {
        float s1 = 0.f, s2 = 0.f;
#pragma unroll
        for (int j = 0; j < 8; ++j) {
            acc[i][j] += bb[j];
            s1 += acc[i][j];
            s2 += acc[i][j] * acc[i][j];
        }
#pragma unroll
        for (int m = 16; m; m >>= 1) { s1 += __shfl_xor(s1, m); s2 += __shfl_xor(s2, m); }
        float mu = s1 * (1.0f / HDIM);
        float var = s2 * (1.0f / HDIM) - mu * mu;
        float inv = 1.0f / sqrtf(var + 1e-5f);
        float4 o0, o1;
        o0.x = (acc[i][0] - mu) * inv * lg[0] + lb[0];
        o0.y = (acc[i][1] - mu) * inv * lg[1] + lb[1];
        o0.z = (acc[i][2] - mu) * inv * lg[2] + lb[2];
        o0.w = (acc[i][3] - mu) * inv * lg[3] + lb[3];
        o1.x = (acc[i][4] - mu) * inv * lg[4] + lb[4];
        o1.y = (acc[i][5] - mu) * inv * lg[5] + lb[5];
        o1.z = (acc[i][6] - mu) * inv * lg[6] + lb[6];
        o1.w = (acc[i][7] - mu) * inv * lg[7] + lb[7];
        *(float4*)&h[(rowbase + r0 + i) * HDIM + c0] = o0;
        *(float4*)&h[(rowbase + r0 + i) * HDIM + c0 + 4] = o1;
    }
}

// ---------------- update GEMM: state += silu(h) @ W2 + b2 ----------------
__global__ __launch_bounds__(256, 2)
void gemm_upd(const float* __restrict__ h, const float* __restrict__ W2,
              const float* __restrict__ b2, float* __restrict__ state) {
    __shared__ float As[32 * 260];
    int tid = threadIdx.x;
    size_t rowbase = (size_t)blockIdx.x * 32;
    for (int i = tid; i < 32 * 64; i += 256) {
        int r = i >> 6, q = i & 63;
        float4 v = *(const float4*)&h[(rowbase + r) * HDIM + q * 4];
        v.x = v.x / (1.0f + expf(-v.x));
        v.y = v.y / (1.0f + expf(-v.y));
        v.z = v.z / (1.0f + expf(-v.z));
        v.w = v.w / (1.0f + expf(-v.w));
        *(float4*)&As[r * 260 + q * 4] = v;
    }
    __syncthreads();
    int rg = tid >> 4, cg = tid & 15;
    int r0 = rg * 2, c0 = cg * 8;
    float acc[2][8];
#pragma unroll
    for (int i = 0; i < 2; ++i)
#pragma unroll
        for (int j = 0; j < 8; ++j) acc[i][j] = 0.f;

#pragma unroll 2
    for (int k = 0; k < HDIM; k += 4) {
        float a[2][4];
#pragma unroll
        for (int i = 0; i < 2; ++i) {
            float4 t = *(const float4*)&As[(r0 + i) * 260 + k];
            a[i][0] = t.x; a[i][1] = t.y; a[i][2] = t.z; a[i][3] = t.w;
        }
#pragma unroll
        for (int kk = 0; kk < 4; ++kk) {
            float4 w0 = *(const float4*)&W2[(size_t)(k + kk) * DDIM + c0];
            float4 w1 = *(const float4*)&W2[(size_t)(k + kk) * DDIM + c0 + 4];
            float wv[8] = {w0.x, w0.y, w0.z, w0.w, w1.x, w1.y, w1.z, w1.w};
#pragma unroll
            for (int i = 0; i < 2; ++i)
#pragma unroll
                for (int j = 0; j < 8; ++j) acc[i][j] += a[i][kk] * wv[j];
        }
    }
    float4 bz0 = *(const float4*)&b2[c0];
    float4 bz1 = *(const float4*)&b2[c0 + 4];
    float bz[8] = {bz0.x, bz0.y, bz0.z, bz0.w, bz1.x, bz1.y, bz1.z, bz1.w};
#pragma unroll
    for (int i = 0; i < 2; ++i) {
        size_t off = (rowbase + r0 + i) * DDIM + c0;
        float4 s0 = *(const float4*)&state[off];
        float4 s1 = *(const float4*)&state[off + 4];
        s0.x += acc[i][0] + bz[0]; s0.y += acc[i][1] + bz[1];
        s0.z += acc[i][2] + bz[2]; s0.w += acc[i][3] + bz[3];
        s1.x += acc[i][4] + bz[4]; s1.y += acc[i][5] + bz[5];
        s1.z += acc[i][6] + bz[6]; s1.w += acc[i][7] + bz[7];
        *(float4*)&state[off] = s0;
        *(float4*)&state[off + 4] = s1;
    }
}

// ---------------- final: mean over N, then @ Wo + bo ----------------
__global__ void partial_mean_kernel(const float* __restrict__ state, float* __restrict__ partial) {
    int b = blockIdx.y, seg = blockIdx.x, tid = threadIdx.x;  // 128 threads
    const float* sp = state + ((size_t)b * NN + (size_t)seg * 128) * DDIM;
    float acc = 0.f;
    for (int i = 0; i < 128; ++i) acc += sp[(size_t)i * DDIM + tid];
    partial[((size_t)b * 32 + seg) * DDIM + tid] = acc;
}

__global__ void final_out_kernel(const float* __restrict__ partial, const float* __restrict__ Wo,
                                 const float* __restrict__ bo, float* __restrict__ out) {
    __shared__ float mean[BQ][DDIM];
    int tid = threadIdx.x;
    for (int o = tid; o < BQ * DDIM; o += 256) {
        int b = o >> 7, d = o & 127;
        float s = 0.f;
        for (int p = 0; p < 32; ++p) s += partial[((size_t)b * 32 + p) * DDIM + d];
        mean[b][d] = s * (1.0f / NN);
    }
    __syncthreads();
    for (int o = tid; o < BQ * DDIM; o += 256) {
        int b = o >> 7, c = o & 127;
        float acc = bo[c];
        for (int d = 0; d < DDIM; ++d) acc += mean[b][d] * Wo[d * DDIM + c];
        out[o] = acc;
    }
}

extern "C" void kernel_launch(void* const* d_in, const int* in_sizes, int n_in,
                              void* d_out, int out_size, void* d_ws, size_t ws_size,
                              hipStream_t stream) {
    const float* x   = (const float*)d_in[0];
    const float* Wn  = (const float*)d_in[1];
    const float* bn  = (const float*)d_in[2];
    const float* W1  = (const float*)d_in[3];
    const float* b1  = (const float*)d_in[4];
    const float* lng = (const float*)d_in[5];
    const float* lnb = (const float*)d_in[6];
    const float* W2  = (const float*)d_in[7];
    const float* b2  = (const float*)d_in[8];
    const float* Wo  = (const float*)d_in[9];
    const float* bo  = (const float*)d_in[10];
    float* out = (float*)d_out;

    float* ws      = (float*)d_ws;
    float* state   = ws;                                        // R*128 f32
    float* keysagg = state + (size_t)RTOT * DDIM;               // R*256 f32
    float* hbuf    = keysagg + (size_t)RTOT * HDIM;             // R*256 f32
    unsigned short* khi_b = (unsigned short*)hbuf;              // R*256 bf16
    unsigned short* klo_b = khi_b + (size_t)RTOT * HDIM;        // R*256 bf16
    float* Mbuf    = hbuf;                                      // R*128 f32 (after sim)
    float* partial = hbuf + (size_t)RTOT * HDIM;                // B*32*128
    int*   idxbuf  = (int*)(partial + (size_t)BQ * 32 * DDIM);  // R*8 ints

    hipMemcpyAsync(state, x, (size_t)RTOT * DDIM * sizeof(float),
                   hipMemcpyDeviceToDevice, stream);

    for (int step = 0; step < 3; ++step) {
        gemm_keys<<<RTOT / 32, 256, 0, stream>>>(state, Wn, bn, khi_b, klo_b);
        sim_topk_kernel<<<512, 256, 0, stream>>>(khi_b, klo_b, idxbuf);
        gather_mean_kernel<<<RTOT / 2, 256, 0, stream>>>(state, idxbuf, Mbuf);
        gemm_d_h<<<RTOT / 32, 256, 0, stream>>>(Mbuf, Wn, bn, keysagg);
        gemm_ln<<<RTOT / 32, 256, 0, stream>>>(state, keysagg, W1, b1, lng, lnb, hbuf);
        gemm_upd<<<RTOT / 32, 256, 0, stream>>>(hbuf, W2, b2, state);
    }
    partial_mean_kernel<<<dim3(32, BQ), 128, 0, stream>>>(state, partial);
    final_out_kernel<<<1, 256, 0, stream>>>(partial, Wo, bo, out);
}